// Round 2
// baseline (617.585 us; speedup 1.0000x reference)
//
#include <hip/hip_runtime.h>
#include <stdint.h>

typedef __bf16 bf16x8 __attribute__((ext_vector_type(8)));
typedef float  f32x4  __attribute__((ext_vector_type(4)));

#define DEV __device__ __forceinline__

constexpr int Bc = 4, S = 2048, D = 1024, Hh = 16, DH = 64;
constexpr int Kdim = 1024;   // inner K of both GEMMs

DEV unsigned short f2bf(float f) {
    uint32_t u = __builtin_bit_cast(uint32_t, f);
    u += 0x7fff + ((u >> 16) & 1);   // RNE
    return (unsigned short)(u >> 16);
}
DEV bf16x8 ld8(const unsigned short* p) {
    uint4 u = *(const uint4*)p;
    return __builtin_bit_cast(bf16x8, u);
}
DEV uint4 pack8(float4 a, float4 b) {
    union { uint4 u; unsigned short s[8]; } r;
    r.s[0] = f2bf(a.x); r.s[1] = f2bf(a.y); r.s[2] = f2bf(a.z); r.s[3] = f2bf(a.w);
    r.s[4] = f2bf(b.x); r.s[5] = f2bf(b.y); r.s[6] = f2bf(b.z); r.s[7] = f2bf(b.w);
    return r.u;
}

// ---------- weight transpose + cvt (f32 [rows][cols] -> bf16 [cols][rows]) ------
__global__ __launch_bounds__(256) void transpose_cvt(const float* __restrict__ in,
                                                     unsigned short* __restrict__ out,
                                                     int rows, int cols) {
    __shared__ float t[32][33];
    int tx = threadIdx.x & 31, ty = threadIdx.x >> 5;  // 32 x 8
    int c = blockIdx.x * 32 + tx;
    int rbase = blockIdx.y * 32;
    for (int rr = 0; rr < 32; rr += 8)
        t[ty + rr][tx] = in[(size_t)(rbase + ty + rr) * cols + c];
    __syncthreads();
    int orbase = blockIdx.x * 32;
    for (int rr = 0; rr < 32; rr += 8)
        out[(size_t)(orbase + ty + rr) * rows + rbase + tx] = f2bf(t[tx][ty + rr]);
}

// ---------- GEMM: C[M,N] = A_f32[M,K] * Bt_bf16[N,K]^T + bias_f32 ---------------
// mode 0: scatter bf16 into q/k/v [B,H,S,DH];  mode 1: write f32 outf [M,N]
__global__ __launch_bounds__(256) void gemm_bt(const float* __restrict__ A,
                                               const unsigned short* __restrict__ Bt,
                                               const float* __restrict__ bias,
                                               int mode,
                                               unsigned short* __restrict__ qo,
                                               unsigned short* __restrict__ ko,
                                               unsigned short* __restrict__ vo,
                                               float* __restrict__ outf) {
    __shared__ __align__(16) unsigned short As[128 * 32];
    __shared__ __align__(16) unsigned short Bs[128 * 32];
    const int tid = threadIdx.x;
    const int wave = tid >> 6, lane = tid & 63, g = lane >> 4, ln = lane & 15;
    const int wm = wave >> 1, wn = wave & 1;          // 2x2 wave grid, 64x64 each
    const int m0 = blockIdx.y * 128, n0 = blockIdx.x * 128;

    f32x4 acc[4][4];
    for (int i = 0; i < 4; i++)
        for (int j = 0; j < 4; j++) acc[i][j] = f32x4{0.f, 0.f, 0.f, 0.f};

    for (int k0 = 0; k0 < Kdim; k0 += 32) {
        for (int c = 0; c < 2; c++) {
            int e = c * 2048 + tid * 8;               // flat elem in [128][32] tile
            int row = e >> 5, col = e & 31;
            const float* ap = A + (size_t)(m0 + row) * Kdim + k0 + col;
            float4 f0 = *(const float4*)ap;
            float4 f1 = *(const float4*)(ap + 4);
            *(uint4*)(As + e) = pack8(f0, f1);
            *(uint4*)(Bs + e) = *(const uint4*)(Bt + (size_t)(n0 + row) * Kdim + k0 + col);
        }
        __syncthreads();
        bf16x8 af[4], bfr[4];
        for (int t = 0; t < 4; t++) af[t]  = ld8(As + (wm * 64 + t * 16 + ln) * 32 + g * 8);
        for (int t = 0; t < 4; t++) bfr[t] = ld8(Bs + (wn * 64 + t * 16 + ln) * 32 + g * 8);
        for (int mt = 0; mt < 4; mt++)
            for (int nt = 0; nt < 4; nt++)
                acc[mt][nt] = __builtin_amdgcn_mfma_f32_16x16x32_bf16(af[mt], bfr[nt], acc[mt][nt], 0, 0, 0);
        __syncthreads();
    }

    // epilogue: C/D layout col=lane&15, row=(lane>>4)*4+reg
    for (int mt = 0; mt < 4; mt++)
        for (int nt = 0; nt < 4; nt++)
            for (int r = 0; r < 4; r++) {
                int m = m0 + wm * 64 + mt * 16 + g * 4 + r;
                int n = n0 + wn * 64 + nt * 16 + ln;
                float val = acc[mt][nt][r] + bias[n];
                if (mode == 0) {
                    int which = n >> 10, rem = n & 1023;
                    unsigned short* dst = (which == 0) ? qo : ((which == 1) ? ko : vo);
                    int hh = rem >> 6, dd = rem & 63;
                    int b = m >> 11, s = m & 2047;
                    dst[((size_t)((b << 4) + hh) * S + s) * DH + dd] = f2bf(val);
                } else {
                    outf[(size_t)m * 1024 + n] = val;
                }
            }
}

// ---------- flash attention: causal, scale 1/8, bf16 in, f32 out ----------------
__global__ __launch_bounds__(256) void attn_fwd(const unsigned short* __restrict__ qg,
                                                const unsigned short* __restrict__ kg,
                                                const unsigned short* __restrict__ vg,
                                                float* __restrict__ og) {
    __shared__ __align__(16) unsigned short Vt[64][136];   // V^T tile, padded
    __shared__ __align__(16) unsigned short P[128][136];   // probs, per-wave 32-row slices
    const int qi = blockIdx.x, bh = blockIdx.y;
    const size_t base = (size_t)bh * S * DH;
    const unsigned short* qp = qg + base;
    const unsigned short* kp = kg + base;
    const unsigned short* vp = vg + base;
    const int tid = threadIdx.x, wave = tid >> 6, lane = tid & 63, g = lane >> 4, ln = lane & 15;
    const int q0 = qi * 128, wq = wave * 32;   // this wave owns q rows [q0+wq, q0+wq+32)

    // Q fragments straight from global (A-operand layout: m=lane&15, k=(lane>>4)*8+j)
    bf16x8 qf[2][2];
    for (int rt = 0; rt < 2; rt++)
        for (int ks = 0; ks < 2; ks++)
            qf[rt][ks] = ld8(qp + (size_t)(q0 + wq + rt * 16 + ln) * DH + ks * 32 + g * 8);

    f32x4 o[2][4];
    float mrow[2][4], lrow[2][4];
    for (int rt = 0; rt < 2; rt++) {
        for (int dt = 0; dt < 4; dt++) o[rt][dt] = f32x4{0.f, 0.f, 0.f, 0.f};
        for (int r = 0; r < 4; r++) { mrow[rt][r] = -1e30f; lrow[rt][r] = 0.f; }
    }

    for (int j = 0; j <= qi; j++) {
        // stage V^T (coalesced global read, scalar LDS transpose writes)
        for (int c = 0; c < 4; c++) {
            int e = c * 2048 + tid * 8;
            int kkr = e >> 6, d0 = e & 63;
            union { uint4 u4; unsigned short s[8]; } cv;
            cv.u4 = *(const uint4*)(vp + (size_t)(j * 128 + kkr) * DH + d0);
            for (int i = 0; i < 8; i++) Vt[d0 + i][kkr] = cv.s[i];
        }
        __syncthreads();

        // scores: S = Q K^T (K b-frags direct from global; both operands K-contig)
        f32x4 s[2][8];
        for (int ct = 0; ct < 8; ct++) {
            const unsigned short* kr = kp + (size_t)(j * 128 + ct * 16 + ln) * DH + g * 8;
            bf16x8 kf0 = ld8(kr);
            bf16x8 kf1 = ld8(kr + 32);
            for (int rt = 0; rt < 2; rt++) {
                f32x4 t = f32x4{0.f, 0.f, 0.f, 0.f};
                t = __builtin_amdgcn_mfma_f32_16x16x32_bf16(qf[rt][0], kf0, t, 0, 0, 0);
                t = __builtin_amdgcn_mfma_f32_16x16x32_bf16(qf[rt][1], kf1, t, 0, 0, 0);
                s[rt][ct] = t;
            }
        }
        for (int rt = 0; rt < 2; rt++)
            for (int ct = 0; ct < 8; ct++) s[rt][ct] *= 0.125f;
        if (j == qi) {   // diagonal tile: causal mask
            for (int rt = 0; rt < 2; rt++)
                for (int ct = 0; ct < 8; ct++)
                    for (int r = 0; r < 4; r++) {
                        int qrow = wq + rt * 16 + g * 4 + r;
                        int kcol = ct * 16 + ln;
                        if (kcol > qrow) s[rt][ct][r] = -1e30f;
                    }
        }
        // online softmax (rows are wave-private: shuffle-only reduction over 16 lanes)
        for (int rt = 0; rt < 2; rt++)
            for (int r = 0; r < 4; r++) {
                float mx = -1e30f;
                for (int ct = 0; ct < 8; ct++) mx = fmaxf(mx, s[rt][ct][r]);
                for (int d = 1; d < 16; d <<= 1) mx = fmaxf(mx, __shfl_xor(mx, d));
                float mold = mrow[rt][r];
                float mnew = fmaxf(mold, mx);
                float alpha = __expf(mold - mnew);
                float rs = 0.f;
                for (int ct = 0; ct < 8; ct++) {
                    float p = __expf(s[rt][ct][r] - mnew);
                    s[rt][ct][r] = p;
                    rs += p;
                }
                for (int d = 1; d < 16; d <<= 1) rs += __shfl_xor(rs, d);
                lrow[rt][r] = lrow[rt][r] * alpha + rs;
                mrow[rt][r] = mnew;
                for (int dt = 0; dt < 4; dt++) o[rt][dt][r] *= alpha;   // per-row rescale
            }
        // P: C-layout regs -> LDS (so we can re-read in A-layout)
        for (int rt = 0; rt < 2; rt++)
            for (int ct = 0; ct < 8; ct++)
                for (int r = 0; r < 4; r++)
                    P[wq + rt * 16 + g * 4 + r][ct * 16 + ln] = f2bf(s[rt][ct][r]);

        // O += P V   (same-wave LDS RAW: DS ops are in-order per wave)
        for (int ks4 = 0; ks4 < 4; ks4++) {
            bf16x8 pf[2], vf[4];
            for (int rt = 0; rt < 2; rt++) pf[rt] = ld8(&P[wq + rt * 16 + ln][ks4 * 32 + g * 8]);
            for (int dt = 0; dt < 4; dt++) vf[dt] = ld8(&Vt[dt * 16 + ln][ks4 * 32 + g * 8]);
            for (int rt = 0; rt < 2; rt++)
                for (int dt = 0; dt < 4; dt++)
                    o[rt][dt] = __builtin_amdgcn_mfma_f32_16x16x32_bf16(pf[rt], vf[dt], o[rt][dt], 0, 0, 0);
        }
        __syncthreads();   // all waves done with Vt before next stage
    }

    // epilogue: merge heads -> [B,S,D] f32
    int b = bh >> 4, h = bh & 15;
    for (int rt = 0; rt < 2; rt++)
        for (int dt = 0; dt < 4; dt++)
            for (int r = 0; r < 4; r++) {
                int srow = q0 + wq + rt * 16 + g * 4 + r;
                int dh = dt * 16 + ln;
                float val = o[rt][dt][r] / lrow[rt][r];
                og[((size_t)(b * S + srow)) * D + h * DH + dh] = val;
            }
}

extern "C" void kernel_launch(void* const* d_in, const int* in_sizes, int n_in,
                              void* d_out, int out_size, void* d_ws, size_t ws_size,
                              hipStream_t stream) {
    (void)in_sizes; (void)n_in; (void)out_size; (void)ws_size;
    const float* x      = (const float*)d_in[0];  // [B,S,D] f32
    const float* w_attn = (const float*)d_in[1];  // [D,3D]  f32
    const float* b_attn = (const float*)d_in[2];  // [3D]    f32
    const float* w_proj = (const float*)d_in[3];  // [D,D]   f32
    const float* b_proj = (const float*)d_in[4];  // [D]     f32

    char* ws = (char*)d_ws;
    unsigned short* wattn_t = (unsigned short*)ws;                       // [3072][1024] bf16
    unsigned short* wproj_t = (unsigned short*)(ws + 6291456);           // [1024][1024] bf16
    unsigned short* qb      = (unsigned short*)(ws + 8388608);           // [B,H,S,DH] bf16
    unsigned short* kb      = (unsigned short*)(ws + 8388608 + 16777216);
    unsigned short* vb      = (unsigned short*)(ws + 8388608 + 2 * 16777216);
    float*          ao      = (float*)         (ws + 8388608 + 3 * 16777216); // [B,S,D] f32

    transpose_cvt<<<dim3(96, 32), 256, 0, stream>>>(w_attn, wattn_t, 1024, 3072);
    transpose_cvt<<<dim3(32, 32), 256, 0, stream>>>(w_proj, wproj_t, 1024, 1024);
    gemm_bt<<<dim3(24, 64), 256, 0, stream>>>(x, wattn_t, b_attn, 0, qb, kb, vb, nullptr);
    attn_fwd<<<dim3(16, 64), 256, 0, stream>>>(qb, kb, vb, ao);
    gemm_bt<<<dim3(8, 64), 256, 0, stream>>>(ao, wproj_t, b_proj, 1,
                                             nullptr, nullptr, nullptr, (float*)d_out);
}

// Round 3
// 485.079 us; speedup vs baseline: 1.2732x; 1.2732x over previous
//
#include <hip/hip_runtime.h>
#include <stdint.h>

typedef __bf16 bf16x8 __attribute__((ext_vector_type(8)));
typedef float  f32x4  __attribute__((ext_vector_type(4)));

#define DEV __device__ __forceinline__

constexpr int Bc = 4, S = 2048, D = 1024, Hh = 16, DH = 64;
constexpr int Kdim = 1024;   // inner K of both GEMMs

DEV unsigned short f2bf(float f) {
    uint32_t u = __builtin_bit_cast(uint32_t, f);
    u += 0x7fff + ((u >> 16) & 1);   // RNE
    return (unsigned short)(u >> 16);
}
DEV bf16x8 ld8(const unsigned short* p) {
    uint4 u = *(const uint4*)p;
    return __builtin_bit_cast(bf16x8, u);
}
DEV uint4 pack8(float4 a, float4 b) {
    union { uint4 u; unsigned short s[8]; } r;
    r.s[0] = f2bf(a.x); r.s[1] = f2bf(a.y); r.s[2] = f2bf(a.z); r.s[3] = f2bf(a.w);
    r.s[4] = f2bf(b.x); r.s[5] = f2bf(b.y); r.s[6] = f2bf(b.z); r.s[7] = f2bf(b.w);
    return r.u;
}

// ---------- weight transpose + cvt (f32 [rows][cols] -> bf16 [cols][rows]) ------
__global__ __launch_bounds__(256) void transpose_cvt(const float* __restrict__ in,
                                                     unsigned short* __restrict__ out,
                                                     int rows, int cols) {
    __shared__ float t[32][33];
    int tx = threadIdx.x & 31, ty = threadIdx.x >> 5;  // 32 x 8
    int c = blockIdx.x * 32 + tx;
    int rbase = blockIdx.y * 32;
    for (int rr = 0; rr < 32; rr += 8)
        t[ty + rr][tx] = in[(size_t)(rbase + ty + rr) * cols + c];
    __syncthreads();
    int orbase = blockIdx.x * 32;
    for (int rr = 0; rr < 32; rr += 8)
        out[(size_t)(orbase + ty + rr) * rows + rbase + tx] = f2bf(t[tx][ty + rr]);
}

// ---------- GEMM: C[M,N] = A_f32[M,K] * Bt_bf16[N,K]^T + bias_f32 ---------------
// mode 0: scatter bf16 into q/k [B,H,S,DH] and V TRANSPOSED [B,H,DH,S]
// mode 1: write f32 outf [M,N]
__global__ __launch_bounds__(256) void gemm_bt(const float* __restrict__ A,
                                               const unsigned short* __restrict__ Bt,
                                               const float* __restrict__ bias,
                                               int mode,
                                               unsigned short* __restrict__ qo,
                                               unsigned short* __restrict__ ko,
                                               unsigned short* __restrict__ vo,
                                               float* __restrict__ outf) {
    __shared__ __align__(16) unsigned short As[128 * 32];
    __shared__ __align__(16) unsigned short Bs[128 * 32];
    const int tid = threadIdx.x;
    const int wave = tid >> 6, lane = tid & 63, g = lane >> 4, ln = lane & 15;
    const int wm = wave >> 1, wn = wave & 1;          // 2x2 wave grid, 64x64 each
    const int m0 = blockIdx.y * 128, n0 = blockIdx.x * 128;

    f32x4 acc[4][4];
    for (int i = 0; i < 4; i++)
        for (int j = 0; j < 4; j++) acc[i][j] = f32x4{0.f, 0.f, 0.f, 0.f};

    for (int k0 = 0; k0 < Kdim; k0 += 32) {
        for (int c = 0; c < 2; c++) {
            int e = c * 2048 + tid * 8;               // flat elem in [128][32] tile
            int row = e >> 5, col = e & 31;
            const float* ap = A + (size_t)(m0 + row) * Kdim + k0 + col;
            float4 f0 = *(const float4*)ap;
            float4 f1 = *(const float4*)(ap + 4);
            *(uint4*)(As + e) = pack8(f0, f1);
            *(uint4*)(Bs + e) = *(const uint4*)(Bt + (size_t)(n0 + row) * Kdim + k0 + col);
        }
        __syncthreads();
        bf16x8 af[4], bfr[4];
        for (int t = 0; t < 4; t++) af[t]  = ld8(As + (wm * 64 + t * 16 + ln) * 32 + g * 8);
        for (int t = 0; t < 4; t++) bfr[t] = ld8(Bs + (wn * 64 + t * 16 + ln) * 32 + g * 8);
        for (int mt = 0; mt < 4; mt++)
            for (int nt = 0; nt < 4; nt++)
                acc[mt][nt] = __builtin_amdgcn_mfma_f32_16x16x32_bf16(af[mt], bfr[nt], acc[mt][nt], 0, 0, 0);
        __syncthreads();
    }

    // epilogue: C/D layout col=lane&15, row=(lane>>4)*4+reg
    for (int mt = 0; mt < 4; mt++)
        for (int nt = 0; nt < 4; nt++)
            for (int r = 0; r < 4; r++) {
                int m = m0 + wm * 64 + mt * 16 + g * 4 + r;
                int n = n0 + wn * 64 + nt * 16 + ln;
                float val = acc[mt][nt][r] + bias[n];
                if (mode == 0) {
                    int which = n >> 10, rem = n & 1023;
                    int hh = rem >> 6, dd = rem & 63;
                    int b = m >> 11, s = m & 2047;
                    int bh = (b << 4) + hh;
                    if (which == 0)      qo[((size_t)bh * S + s) * DH + dd] = f2bf(val);
                    else if (which == 1) ko[((size_t)bh * S + s) * DH + dd] = f2bf(val);
                    else                 vo[((size_t)bh * DH + dd) * S + s] = f2bf(val);  // V^T
                } else {
                    outf[(size_t)m * 1024 + n] = val;
                }
            }
}

// ---------- flash attention, S^T formulation, barrier-free ----------------------
// scores computed as S^T = K·Q^T so softmax rows live per-lane (col=lane&15);
// P written to per-wave-private LDS rows as b64; V^T fragments direct from global.
__global__ __launch_bounds__(128) void attn_fwd(const unsigned short* __restrict__ qg,
                                                const unsigned short* __restrict__ kg,
                                                const unsigned short* __restrict__ vtg,
                                                float* __restrict__ og) {
    __shared__ __align__(16) unsigned short P[64][136];   // per-wave rows [wq..wq+32)
    const int bx = blockIdx.x, bh = blockIdx.y;
    const size_t base = (size_t)bh * S * DH;
    const unsigned short* qp  = qg  + base;
    const unsigned short* kp  = kg  + base;
    const unsigned short* vtp = vtg + base;               // [DH][S]
    const int tid = threadIdx.x, wave = tid >> 6, lane = tid & 63;
    const int g = lane >> 4, ln = lane & 15;
    const int qt = 31 - bx;                               // heavy q-tiles dispatch first
    const int q0 = qt * 64, wq = wave * 32;               // wave owns q rows [q0+wq, +32)
    const int jmax = qt >> 1;
    const int b = bh >> 4, h = bh & 15;
    const int srcl = (lane & 48) | (lane >> 2);           // placeholder overwritten below

    // Q B-frags (B-layout: n=lane&15, k=(lane>>4)*8+j), rows q0+wq+nt*16+ln
    bf16x8 qf[2][2];
#pragma unroll
    for (int nt = 0; nt < 2; nt++)
#pragma unroll
        for (int kc = 0; kc < 2; kc++)
            qf[nt][kc] = ld8(qp + (size_t)(q0 + wq + nt * 16 + ln) * DH + kc * 32 + g * 8);

    f32x4 o[2][4];
    float m_[2], l_[2];
#pragma unroll
    for (int rt = 0; rt < 2; rt++) {
#pragma unroll
        for (int dt = 0; dt < 4; dt++) o[rt][dt] = f32x4{0.f, 0.f, 0.f, 0.f};
        m_[rt] = -1e30f; l_[rt] = 0.f;
    }
    (void)srcl;

    for (int j = 0; j <= jmax; j++) {
        const unsigned short* kjp = kp + (size_t)j * 128 * DH;
        // S^T tile: rows kv (128), cols qrow (32).  st[mt][nt] C-layout:
        //   kv = mt*16 + g*4 + r,  qrow = nt*16 + ln
        f32x4 st[8][2];
#pragma unroll
        for (int mt = 0; mt < 8; mt++) { st[mt][0] = f32x4{0.f,0.f,0.f,0.f}; st[mt][1] = f32x4{0.f,0.f,0.f,0.f}; }
#pragma unroll
        for (int kc = 0; kc < 2; kc++) {
            bf16x8 kf[8];
#pragma unroll
            for (int mt = 0; mt < 8; mt++)
                kf[mt] = ld8(kjp + (size_t)(mt * 16 + ln) * DH + kc * 32 + g * 8);
#pragma unroll
            for (int mt = 0; mt < 8; mt++) {
                st[mt][0] = __builtin_amdgcn_mfma_f32_16x16x32_bf16(kf[mt], qf[0][kc], st[mt][0], 0, 0, 0);
                st[mt][1] = __builtin_amdgcn_mfma_f32_16x16x32_bf16(kf[mt], qf[1][kc], st[mt][1], 0, 0, 0);
            }
        }
        if (j == jmax) {   // diagonal: mask kv_global > q_global
#pragma unroll
            for (int mt = 0; mt < 8; mt++)
#pragma unroll
                for (int nt = 0; nt < 2; nt++)
#pragma unroll
                    for (int r = 0; r < 4; r++) {
                        int kvg = j * 128 + mt * 16 + g * 4 + r;
                        int qgl = q0 + wq + nt * 16 + ln;
                        if (kvg > qgl) st[mt][nt][r] = -3e38f;
                    }
        }
        // online softmax per q-row (lane-resident), scale 1/8 folded into exp
        float alpha[2];
#pragma unroll
        for (int nt = 0; nt < 2; nt++) {
            f32x4 mm = st[0][nt];
#pragma unroll
            for (int mt = 1; mt < 8; mt++)
#pragma unroll
                for (int e = 0; e < 4; e++) mm[e] = fmaxf(mm[e], st[mt][nt][e]);
            float mx = fmaxf(fmaxf(mm[0], mm[1]), fmaxf(mm[2], mm[3]));
            mx = fmaxf(mx, __shfl_xor(mx, 16));
            mx = fmaxf(mx, __shfl_xor(mx, 32));
            float mnew = fmaxf(m_[nt], mx);
            alpha[nt] = __expf((m_[nt] - mnew) * 0.125f);
            f32x4 sv = f32x4{0.f, 0.f, 0.f, 0.f};
#pragma unroll
            for (int mt = 0; mt < 8; mt++) {
                f32x4 p;
#pragma unroll
                for (int e = 0; e < 4; e++) p[e] = __expf((st[mt][nt][e] - mnew) * 0.125f);
                st[mt][nt] = p;
                sv += p;
            }
            float rs = (sv[0] + sv[1]) + (sv[2] + sv[3]);
            rs += __shfl_xor(rs, 16);
            rs += __shfl_xor(rs, 32);
            l_[nt] = l_[nt] * alpha[nt] + rs;
            m_[nt] = mnew;
        }
        // pack P (truncate f32->bf16) and write per-wave rows as b64
#pragma unroll
        for (int nt = 0; nt < 2; nt++)
#pragma unroll
            for (int mt = 0; mt < 8; mt++) {
                uint4 u = __builtin_bit_cast(uint4, st[mt][nt]);
                uint2 w;
                w.x = (u.y & 0xFFFF0000u) | (u.x >> 16);
                w.y = (u.w & 0xFFFF0000u) | (u.z >> 16);
                *(uint2*)&P[wq + nt * 16 + ln][mt * 16 + g * 4] = w;
            }
        // rescale O rows (C-layout row = g*4+r) by alpha from stat lane ln'=g*4+r
#pragma unroll
        for (int r = 0; r < 4; r++) {
            int sl = (lane & 48) + g * 4 + r;
            float a0 = __shfl(alpha[0], sl);
            float a1 = __shfl(alpha[1], sl);
#pragma unroll
            for (int dt = 0; dt < 4; dt++) { o[0][dt][r] *= a0; o[1][dt][r] *= a1; }
        }
        // O += P V  (A = P from same-wave LDS, B = V^T rows direct from global)
#pragma unroll
        for (int kc = 0; kc < 4; kc++) {
            bf16x8 pf[2], vf[4];
#pragma unroll
            for (int rt = 0; rt < 2; rt++) pf[rt] = ld8(&P[wq + rt * 16 + ln][kc * 32 + g * 8]);
#pragma unroll
            for (int dt = 0; dt < 4; dt++)
                vf[dt] = ld8(vtp + (size_t)(dt * 16 + ln) * S + j * 128 + kc * 32 + g * 8);
#pragma unroll
            for (int rt = 0; rt < 2; rt++)
#pragma unroll
                for (int dt = 0; dt < 4; dt++)
                    o[rt][dt] = __builtin_amdgcn_mfma_f32_16x16x32_bf16(pf[rt], vf[dt], o[rt][dt], 0, 0, 0);
        }
    }

    // epilogue: O row g*4+r gets 1/l from stat lane ln'=g*4+r; merge heads f32
#pragma unroll
    for (int r = 0; r < 4; r++) {
        int sl = (lane & 48) + g * 4 + r;
        float il0 = 1.f / __shfl(l_[0], sl);
        float il1 = 1.f / __shfl(l_[1], sl);
#pragma unroll
        for (int dt = 0; dt < 4; dt++) {
            int col = h * DH + dt * 16 + ln;
            int r0 = q0 + wq + g * 4 + r;          // rt = 0
            int r1 = r0 + 16;                      // rt = 1
            og[((size_t)(b * S + r0)) * D + col] = o[0][dt][r] * il0;
            og[((size_t)(b * S + r1)) * D + col] = o[1][dt][r] * il1;
        }
    }
}

extern "C" void kernel_launch(void* const* d_in, const int* in_sizes, int n_in,
                              void* d_out, int out_size, void* d_ws, size_t ws_size,
                              hipStream_t stream) {
    (void)in_sizes; (void)n_in; (void)out_size; (void)ws_size;
    const float* x      = (const float*)d_in[0];  // [B,S,D] f32
    const float* w_attn = (const float*)d_in[1];  // [D,3D]  f32
    const float* b_attn = (const float*)d_in[2];  // [3D]    f32
    const float* w_proj = (const float*)d_in[3];  // [D,D]   f32
    const float* b_proj = (const float*)d_in[4];  // [D]     f32

    char* ws = (char*)d_ws;
    unsigned short* wattn_t = (unsigned short*)ws;                       // [3072][1024] bf16
    unsigned short* wproj_t = (unsigned short*)(ws + 6291456);           // [1024][1024] bf16
    unsigned short* qb      = (unsigned short*)(ws + 8388608);           // [B,H,S,DH] bf16
    unsigned short* kb      = (unsigned short*)(ws + 8388608 + 16777216);
    unsigned short* vtb     = (unsigned short*)(ws + 8388608 + 2 * 16777216); // [B,H,DH,S] bf16
    float*          ao      = (float*)         (ws + 8388608 + 3 * 16777216); // [B,S,D] f32

    transpose_cvt<<<dim3(96, 32), 256, 0, stream>>>(w_attn, wattn_t, 1024, 3072);
    transpose_cvt<<<dim3(32, 32), 256, 0, stream>>>(w_proj, wproj_t, 1024, 1024);
    gemm_bt<<<dim3(24, 64), 256, 0, stream>>>(x, wattn_t, b_attn, 0, qb, kb, vtb, nullptr);
    attn_fwd<<<dim3(32, 64), 128, 0, stream>>>(qb, kb, vtb, ao);
    gemm_bt<<<dim3(8, 64), 256, 0, stream>>>(ao, wproj_t, b_proj, 1,
                                             nullptr, nullptr, nullptr, (float*)d_out);
}

// Round 4
// 480.938 us; speedup vs baseline: 1.2841x; 1.0086x over previous
//
#include <hip/hip_runtime.h>
#include <stdint.h>

typedef __bf16 bf16x8 __attribute__((ext_vector_type(8)));
typedef float  f32x4  __attribute__((ext_vector_type(4)));

#define DEV __device__ __forceinline__

constexpr int Bc = 4, S = 2048, D = 1024, Hh = 16, DH = 64;
constexpr int Kdim = 1024;   // inner K of both GEMMs

DEV unsigned short f2bf(float f) {
    uint32_t u = __builtin_bit_cast(uint32_t, f);
    u += 0x7fff + ((u >> 16) & 1);   // RNE
    return (unsigned short)(u >> 16);
}
DEV bf16x8 ld8(const unsigned short* p) {
    uint4 u = *(const uint4*)p;
    return __builtin_bit_cast(bf16x8, u);
}
DEV uint4 pack8(float4 a, float4 b) {
    union { uint4 u; unsigned short s[8]; } r;
    r.s[0] = f2bf(a.x); r.s[1] = f2bf(a.y); r.s[2] = f2bf(a.z); r.s[3] = f2bf(a.w);
    r.s[4] = f2bf(b.x); r.s[5] = f2bf(b.y); r.s[6] = f2bf(b.z); r.s[7] = f2bf(b.w);
    return r.u;
}

// ---------- weight transpose + cvt (f32 [rows][cols] -> bf16 [cols][rows]) ------
__global__ __launch_bounds__(256) void transpose_cvt(const float* __restrict__ in,
                                                     unsigned short* __restrict__ out,
                                                     int rows, int cols) {
    __shared__ float t[32][33];
    int tx = threadIdx.x & 31, ty = threadIdx.x >> 5;  // 32 x 8
    int c = blockIdx.x * 32 + tx;
    int rbase = blockIdx.y * 32;
    for (int rr = 0; rr < 32; rr += 8)
        t[ty + rr][tx] = in[(size_t)(rbase + ty + rr) * cols + c];
    __syncthreads();
    int orbase = blockIdx.x * 32;
    for (int rr = 0; rr < 32; rr += 8)
        out[(size_t)(orbase + ty + rr) * rows + rbase + tx] = f2bf(t[tx][ty + rr]);
}

// ---------- GEMM: C[M,N] = A_f32[M,K] * Bt_bf16[N,K]^T + bias_f32 ---------------
// mode 0: scatter bf16 into q/k [B,H,S,DH] and V TRANSPOSED [B,H,DH,S]
// mode 1: write f32 outf [M,N]
__global__ __launch_bounds__(256) void gemm_bt(const float* __restrict__ A,
                                               const unsigned short* __restrict__ Bt,
                                               const float* __restrict__ bias,
                                               int mode,
                                               unsigned short* __restrict__ qo,
                                               unsigned short* __restrict__ ko,
                                               unsigned short* __restrict__ vo,
                                               float* __restrict__ outf) {
    __shared__ __align__(16) unsigned short As[128 * 32];
    __shared__ __align__(16) unsigned short Bs[128 * 32];
    const int tid = threadIdx.x;
    const int wave = tid >> 6, lane = tid & 63, g = lane >> 4, ln = lane & 15;
    const int wm = wave >> 1, wn = wave & 1;          // 2x2 wave grid, 64x64 each
    const int m0 = blockIdx.y * 128, n0 = blockIdx.x * 128;

    f32x4 acc[4][4];
    for (int i = 0; i < 4; i++)
        for (int j = 0; j < 4; j++) acc[i][j] = f32x4{0.f, 0.f, 0.f, 0.f};

    for (int k0 = 0; k0 < Kdim; k0 += 32) {
        for (int c = 0; c < 2; c++) {
            int e = c * 2048 + tid * 8;               // flat elem in [128][32] tile
            int row = e >> 5, col = e & 31;
            const float* ap = A + (size_t)(m0 + row) * Kdim + k0 + col;
            float4 f0 = *(const float4*)ap;
            float4 f1 = *(const float4*)(ap + 4);
            *(uint4*)(As + e) = pack8(f0, f1);
            *(uint4*)(Bs + e) = *(const uint4*)(Bt + (size_t)(n0 + row) * Kdim + k0 + col);
        }
        __syncthreads();
        bf16x8 af[4], bfr[4];
        for (int t = 0; t < 4; t++) af[t]  = ld8(As + (wm * 64 + t * 16 + ln) * 32 + g * 8);
        for (int t = 0; t < 4; t++) bfr[t] = ld8(Bs + (wn * 64 + t * 16 + ln) * 32 + g * 8);
        for (int mt = 0; mt < 4; mt++)
            for (int nt = 0; nt < 4; nt++)
                acc[mt][nt] = __builtin_amdgcn_mfma_f32_16x16x32_bf16(af[mt], bfr[nt], acc[mt][nt], 0, 0, 0);
        __syncthreads();
    }

    // epilogue: C/D layout col=lane&15, row=(lane>>4)*4+reg
    for (int mt = 0; mt < 4; mt++)
        for (int nt = 0; nt < 4; nt++)
            for (int r = 0; r < 4; r++) {
                int m = m0 + wm * 64 + mt * 16 + g * 4 + r;
                int n = n0 + wn * 64 + nt * 16 + ln;
                float val = acc[mt][nt][r] + bias[n];
                if (mode == 0) {
                    int which = n >> 10, rem = n & 1023;
                    int hh = rem >> 6, dd = rem & 63;
                    int b = m >> 11, s = m & 2047;
                    int bh = (b << 4) + hh;
                    if (which == 0)      qo[((size_t)bh * S + s) * DH + dd] = f2bf(val);
                    else if (which == 1) ko[((size_t)bh * S + s) * DH + dd] = f2bf(val);
                    else                 vo[((size_t)bh * DH + dd) * S + s] = f2bf(val);  // V^T
                } else {
                    outf[(size_t)m * 1024 + n] = val;
                }
            }
}

// ---------- flash attention, S^T formulation, barrier-free, paired tiles --------
// Block = 4 waves. Waves 0,1 handle q-tile bx; waves 2,3 handle q-tile 31-bx.
// Total j-iters per block = 17 for every bx -> perfectly uniform grid of
// 1024 blocks = exact full residency (4 blocks/CU at 128 VGPR, 34.8 KB LDS).
__global__ __launch_bounds__(256, 4) void attn_fwd(const unsigned short* __restrict__ qg,
                                                   const unsigned short* __restrict__ kg,
                                                   const unsigned short* __restrict__ vtg,
                                                   float* __restrict__ og) {
    __shared__ __align__(16) unsigned short P[128][136];  // per-wave rows [wave*32 ..)
    const int bx = blockIdx.x, bh = blockIdx.y;
    const size_t base = (size_t)bh * S * DH;
    const unsigned short* qp  = qg  + base;
    const unsigned short* kp  = kg  + base;
    const unsigned short* vtp = vtg + base;               // [DH][S]
    const int tid = threadIdx.x, wave = tid >> 6, lane = tid & 63;
    const int g = lane >> 4, ln = lane & 15;
    const int qt = (wave >> 1) ? (31 - bx) : bx;          // paired triangular tiles
    const int q0 = qt * 64;
    const int wq = (wave & 1) * 32;                       // q-row offset within tile
    const int lq = wave * 32;                             // this wave's LDS P rows
    const int jmax = qt >> 1;
    const int b = bh >> 4, h = bh & 15;

    // Q B-frags (B-layout: n=lane&15, k=(lane>>4)*8+j), rows q0+wq+nt*16+ln
    bf16x8 qf[2][2];
#pragma unroll
    for (int nt = 0; nt < 2; nt++)
#pragma unroll
        for (int kc = 0; kc < 2; kc++)
            qf[nt][kc] = ld8(qp + (size_t)(q0 + wq + nt * 16 + ln) * DH + kc * 32 + g * 8);

    f32x4 o[2][4];
    float m_[2], l_[2];
#pragma unroll
    for (int rt = 0; rt < 2; rt++) {
#pragma unroll
        for (int dt = 0; dt < 4; dt++) o[rt][dt] = f32x4{0.f, 0.f, 0.f, 0.f};
        m_[rt] = -1e30f; l_[rt] = 0.f;
    }

    for (int j = 0; j <= jmax; j++) {
        const unsigned short* kjp = kp + (size_t)j * 128 * DH;
        // S^T tile: rows kv (128), cols qrow (32).  st[mt][nt] C-layout:
        //   kv = mt*16 + g*4 + r,  qrow = nt*16 + ln
        f32x4 st[8][2];
#pragma unroll
        for (int mt = 0; mt < 8; mt++) { st[mt][0] = f32x4{0.f,0.f,0.f,0.f}; st[mt][1] = f32x4{0.f,0.f,0.f,0.f}; }
#pragma unroll
        for (int kc = 0; kc < 2; kc++) {
            bf16x8 kf[8];
#pragma unroll
            for (int mt = 0; mt < 8; mt++)
                kf[mt] = ld8(kjp + (size_t)(mt * 16 + ln) * DH + kc * 32 + g * 8);
#pragma unroll
            for (int mt = 0; mt < 8; mt++) {
                st[mt][0] = __builtin_amdgcn_mfma_f32_16x16x32_bf16(kf[mt], qf[0][kc], st[mt][0], 0, 0, 0);
                st[mt][1] = __builtin_amdgcn_mfma_f32_16x16x32_bf16(kf[mt], qf[1][kc], st[mt][1], 0, 0, 0);
            }
        }
        if (j == jmax) {   // diagonal: mask kv_global > q_global
#pragma unroll
            for (int mt = 0; mt < 8; mt++)
#pragma unroll
                for (int nt = 0; nt < 2; nt++)
#pragma unroll
                    for (int r = 0; r < 4; r++) {
                        int kvg = j * 128 + mt * 16 + g * 4 + r;
                        int qgl = q0 + wq + nt * 16 + ln;
                        if (kvg > qgl) st[mt][nt][r] = -3e38f;
                    }
        }
        // online softmax per q-row (lane-resident), scale 1/8 folded into exp
        float alpha[2];
#pragma unroll
        for (int nt = 0; nt < 2; nt++) {
            f32x4 mm = st[0][nt];
#pragma unroll
            for (int mt = 1; mt < 8; mt++)
#pragma unroll
                for (int e = 0; e < 4; e++) mm[e] = fmaxf(mm[e], st[mt][nt][e]);
            float mx = fmaxf(fmaxf(mm[0], mm[1]), fmaxf(mm[2], mm[3]));
            mx = fmaxf(mx, __shfl_xor(mx, 16));
            mx = fmaxf(mx, __shfl_xor(mx, 32));
            float mnew = fmaxf(m_[nt], mx);
            alpha[nt] = __expf((m_[nt] - mnew) * 0.125f);
            f32x4 sv = f32x4{0.f, 0.f, 0.f, 0.f};
#pragma unroll
            for (int mt = 0; mt < 8; mt++) {
                f32x4 p;
#pragma unroll
                for (int e = 0; e < 4; e++) p[e] = __expf((st[mt][nt][e] - mnew) * 0.125f);
                st[mt][nt] = p;
                sv += p;
            }
            float rs = (sv[0] + sv[1]) + (sv[2] + sv[3]);
            rs += __shfl_xor(rs, 16);
            rs += __shfl_xor(rs, 32);
            l_[nt] = l_[nt] * alpha[nt] + rs;
            m_[nt] = mnew;
        }
        // pack P (truncate f32->bf16) and write per-wave rows as b64
#pragma unroll
        for (int nt = 0; nt < 2; nt++)
#pragma unroll
            for (int mt = 0; mt < 8; mt++) {
                uint4 u = __builtin_bit_cast(uint4, st[mt][nt]);
                uint2 w;
                w.x = (u.y & 0xFFFF0000u) | (u.x >> 16);
                w.y = (u.w & 0xFFFF0000u) | (u.z >> 16);
                *(uint2*)&P[lq + nt * 16 + ln][mt * 16 + g * 4] = w;
            }
        // rescale O rows (C-layout row = g*4+r) by alpha from stat lane ln'=g*4+r
#pragma unroll
        for (int r = 0; r < 4; r++) {
            int sl = (lane & 48) + g * 4 + r;
            float a0 = __shfl(alpha[0], sl);
            float a1 = __shfl(alpha[1], sl);
#pragma unroll
            for (int dt = 0; dt < 4; dt++) { o[0][dt][r] *= a0; o[1][dt][r] *= a1; }
        }
        // O += P V  (A = P from same-wave LDS, B = V^T rows direct from global)
#pragma unroll
        for (int kc = 0; kc < 4; kc++) {
            bf16x8 pf[2], vf[4];
#pragma unroll
            for (int rt = 0; rt < 2; rt++) pf[rt] = ld8(&P[lq + rt * 16 + ln][kc * 32 + g * 8]);
#pragma unroll
            for (int dt = 0; dt < 4; dt++)
                vf[dt] = ld8(vtp + (size_t)(dt * 16 + ln) * S + j * 128 + kc * 32 + g * 8);
#pragma unroll
            for (int rt = 0; rt < 2; rt++)
#pragma unroll
                for (int dt = 0; dt < 4; dt++)
                    o[rt][dt] = __builtin_amdgcn_mfma_f32_16x16x32_bf16(pf[rt], vf[dt], o[rt][dt], 0, 0, 0);
        }
    }

    // epilogue: O row g*4+r gets 1/l from stat lane ln'=g*4+r; merge heads f32
#pragma unroll
    for (int r = 0; r < 4; r++) {
        int sl = (lane & 48) + g * 4 + r;
        float il0 = 1.f / __shfl(l_[0], sl);
        float il1 = 1.f / __shfl(l_[1], sl);
#pragma unroll
        for (int dt = 0; dt < 4; dt++) {
            int col = h * DH + dt * 16 + ln;
            int r0 = q0 + wq + g * 4 + r;          // rt = 0
            int r1 = r0 + 16;                      // rt = 1
            og[((size_t)(b * S + r0)) * D + col] = o[0][dt][r] * il0;
            og[((size_t)(b * S + r1)) * D + col] = o[1][dt][r] * il1;
        }
    }
}

extern "C" void kernel_launch(void* const* d_in, const int* in_sizes, int n_in,
                              void* d_out, int out_size, void* d_ws, size_t ws_size,
                              hipStream_t stream) {
    (void)in_sizes; (void)n_in; (void)out_size; (void)ws_size;
    const float* x      = (const float*)d_in[0];  // [B,S,D] f32
    const float* w_attn = (const float*)d_in[1];  // [D,3D]  f32
    const float* b_attn = (const float*)d_in[2];  // [3D]    f32
    const float* w_proj = (const float*)d_in[3];  // [D,D]   f32
    const float* b_proj = (const float*)d_in[4];  // [D]     f32

    char* ws = (char*)d_ws;
    unsigned short* wattn_t = (unsigned short*)ws;                       // [3072][1024] bf16
    unsigned short* wproj_t = (unsigned short*)(ws + 6291456);           // [1024][1024] bf16
    unsigned short* qb      = (unsigned short*)(ws + 8388608);           // [B,H,S,DH] bf16
    unsigned short* kb      = (unsigned short*)(ws + 8388608 + 16777216);
    unsigned short* vtb     = (unsigned short*)(ws + 8388608 + 2 * 16777216); // [B,H,DH,S] bf16
    float*          ao      = (float*)         (ws + 8388608 + 3 * 16777216); // [B,S,D] f32

    transpose_cvt<<<dim3(96, 32), 256, 0, stream>>>(w_attn, wattn_t, 1024, 3072);
    transpose_cvt<<<dim3(32, 32), 256, 0, stream>>>(w_proj, wproj_t, 1024, 1024);
    gemm_bt<<<dim3(24, 64), 256, 0, stream>>>(x, wattn_t, b_attn, 0, qb, kb, vtb, nullptr);
    attn_fwd<<<dim3(16, 64), 256, 0, stream>>>(qb, kb, vtb, ao);
    gemm_bt<<<dim3(8, 64), 256, 0, stream>>>(ao, wproj_t, b_proj, 1,
                                             nullptr, nullptr, nullptr, (float*)d_out);
}